// Round 1
// baseline (130.999 us; speedup 1.0000x reference)
//
#include <hip/hip_runtime.h>
#include <stdint.h>

#define D 10000
#define LVL 100
#define T 2048
#define TN 2046   // T - NGRAM + 1
#define NW 162    // ceil(D/62) column windows (64 row cols -> 62 out cols per wave)
#define NCHUNK 32 // ceil(TN/64) t-chunks

// ws layout (floats):
//   acc  : float[D]      @ 0
//   mhv  : float[6*D]    @ D
//   idx  : uchar[T*4]    @ byte offset 7*D*4
#define WS_ACC 0
#define WS_MHV (D)
#define WS_IDX_BYTES (7 * D * 4)

// ---------------- K1: idx table, zero acc, MFCC sinusoid HVs ----------------
__global__ __launch_bounds__(256) void k1_prep(
    const float* __restrict__ signals,   // [T,4]
    const float* __restrict__ feat,      // [600]
    const float* __restrict__ mfcc_w,    // [6,D,91]
    const float* __restrict__ mfcc_b,    // [6,D]
    float* __restrict__ ws)
{
    int gid = blockIdx.x * 256 + threadIdx.x;
    float* acc = ws + WS_ACC;
    float* mhv = ws + WS_MHV;
    unsigned char* idxb = (unsigned char*)ws + WS_IDX_BYTES;

    if (gid < D) acc[gid] = 0.f;

    if (gid < T * 4) {
        float s = signals[gid];
        s = fminf(fmaxf(s, 0.f), 1.f);
        float v = rintf(s * 99.0f);     // round-half-even == np.round
        int iv = (int)v;
        iv = iv < 0 ? 0 : (iv > 99 ? 99 : iv);
        idxb[gid] = (unsigned char)iv;
    }

    if (gid < 6 * D) {
        int k = gid / D;
        const float* wp = mfcc_w + (size_t)gid * 91;  // (k*D+d)*91, contiguous per thread
        const float* mf = feat + k * 91;
        float s = 0.f;
        #pragma unroll 7
        for (int f = 0; f < 91; ++f) s = fmaf(wp[f], mf[f], s);
        float b = mfcc_b[gid];
        mhv[gid] = cosf(s + b) * sinf(s);
    }
}

// ---------------- K2: n-gram encode + multiset (the hot kernel) ----------------
// grid = (NW, NCHUNK), block = 64 (one wave).
// Wave computes p-rows at 64 columns rc = (w*62 - 2 + lane) mod D,
// emits 62 output columns via shfl_up rolls, atomicAdd exact-integer partials.
__global__ __launch_bounds__(64) void k2_ngram(
    const float* __restrict__ keys,  // [4,D]
    const float* __restrict__ lw,    // [100,D]
    float* __restrict__ ws)
{
    float* acc = ws + WS_ACC;
    const uint32_t* idxw = (const uint32_t*)((const unsigned char*)ws + WS_IDX_BYTES);

    int w = blockIdx.x;
    int chunk = blockIdx.y;
    int l = threadIdx.x;
    int t0 = chunk * 64;
    int len = min(64, TN - t0);

    int rc = (w * 62 + l + (D - 2)) % D;
    float k0 = keys[rc];
    float k1 = keys[D + rc];
    float k2 = keys[2 * D + rc];
    float k3 = keys[3 * D + rc];

    auto row = [&](int t) -> float {
        uint32_t iw = idxw[t];           // uniform: 4 packed level indices
        int l0 = iw & 0xff;
        int l1 = (iw >> 8) & 0xff;
        int l2 = (iw >> 16) & 0xff;
        int l3 = (iw >> 24);
        float r = k0 * lw[l0 * D + rc];
        r = fmaf(k1, lw[l1 * D + rc], r);
        r = fmaf(k2, lw[l2 * D + rc], r);
        r = fmaf(k3, lw[l3 * D + rc], r);
        return r;
    };

    float a = row(t0);       // p[t]
    float b = row(t0 + 1);   // p[t+1]
    float accv = 0.f;
    for (int t = t0; t < t0 + len; ++t) {
        float c = row(t + 2);                 // p[t+2]
        float a2 = __shfl_up(a, 2, 64);       // p[t][outcol-2]
        float b1 = __shfl_up(b, 1, 64);       // p[t+1][outcol-1]
        accv = fmaf(a2 * b1, c, accv);        // exact small-integer arithmetic
        a = b; b = c;
    }
    int outcol = w * 62 + l - 2;
    if (l >= 2 && outcol < D) atomicAdd(&acc[outcol], accv);
}

// ---------------- K3: 29 sinusoid kernels, comb, hard quantize ----------------
__global__ __launch_bounds__(256) void k3_finish(
    const float* __restrict__ feat,
    const float* __restrict__ feat_w,   // [29,D]
    const float* __restrict__ feat_b,   // [29,D]
    float* __restrict__ out,
    const float* __restrict__ ws)
{
    static const int CF[29] = {547,548,549,551,554,556,557,558,559,560,561,562,563,565,
                               566,567,570,576,580,581,582,583,584,585,588,593,598,599,600};
    int d = blockIdx.x * 256 + threadIdx.x;
    if (d >= D) return;
    const float* acc = ws + WS_ACC;
    const float* mhv = ws + WS_MHV;

    float h[29];
    #pragma unroll
    for (int i = 0; i < 29; ++i) {
        float sel = feat[CF[i] - 1];               // uniform scalar load
        float proj = sel * feat_w[i * D + d];
        h[i] = cosf(proj + feat_b[i * D + d]) * sinf(proj);
    }

    float mf = mhv[d];
    #pragma unroll
    for (int k = 1; k < 6; ++k) mf *= mhv[k * D + d];

    float comb = h[0] * h[8] * h[13]
               + h[1] * h[9] * h[14]
               + h[2] * h[10] * h[15]
               + h[3] * h[4]
               + h[5] * h[7] * h[22] * h[6] * h[23] * h[19] * h[18]
                 * h[20] * h[21] * h[26] * h[28] * h[27]
               + h[11] + h[12]
               + h[16] * h[24]
               + h[17] + h[25]
               + mf;

    float sv = acc[d] * comb;
    out[d] = sv > 0.f ? 1.f : -1.f;
}

extern "C" void kernel_launch(void* const* d_in, const int* in_sizes, int n_in,
                              void* d_out, int out_size, void* d_ws, size_t ws_size,
                              hipStream_t stream) {
    const float* signals = (const float*)d_in[0];
    const float* feat    = (const float*)d_in[1];
    const float* keys    = (const float*)d_in[2];
    const float* lw      = (const float*)d_in[3];
    const float* feat_w  = (const float*)d_in[4];
    const float* feat_b  = (const float*)d_in[5];
    const float* mfcc_w  = (const float*)d_in[6];
    const float* mfcc_b  = (const float*)d_in[7];
    float* ws  = (float*)d_ws;
    float* out = (float*)d_out;

    k1_prep<<<dim3(235), dim3(256), 0, stream>>>(signals, feat, mfcc_w, mfcc_b, ws);
    k2_ngram<<<dim3(NW, NCHUNK), dim3(64), 0, stream>>>(keys, lw, ws);
    k3_finish<<<dim3(40), dim3(256), 0, stream>>>(feat, feat_w, feat_b, out, ws);
}

// Round 2
// 130.087 us; speedup vs baseline: 1.0070x; 1.0070x over previous
//
#include <hip/hip_runtime.h>
#include <stdint.h>

#define D 10000
#define T 2048
#define TN 2046            // T - NGRAM + 1
#define NW 162             // ceil(D/62): 64 row-cols -> 62 out-cols per wave
#define NCHUNK 16
#define TCHUNK 128         // 16*128 = 2048 >= TN
#define NGBLK (NW * NCHUNK)      // 2592 ngram blocks
#define MHVTH (6 * D)            // 60000 mfcc threads
#define MHVBLK ((MHVTH + 63) / 64)  // 938

// ws layout (floats): partial[NCHUNK][D] @ 0 ; mhv[6][D] @ NCHUNK*D
// Every slot is written unconditionally -> no zero-init needed despite 0xAA poison.

// ---------------- kA: fused ngram-encode + MFCC sinusoid HVs ----------------
__global__ __launch_bounds__(64) void kA(
    const float* __restrict__ signals,   // [T,4]
    const float* __restrict__ feat,      // [600]
    const float* __restrict__ keys,      // [4,D]
    const float* __restrict__ lw,        // [100,D]
    const float* __restrict__ mfcc_w,    // [6,D,91]
    const float* __restrict__ mfcc_b,    // [6,D]
    float* __restrict__ ws)
{
    const int bid = blockIdx.x;
    const int l   = threadIdx.x;

    if (bid < NGBLK) {
        // ---- ngram part: one wave, 64 row-cols -> 62 out-cols, TCHUNK t-steps ----
        __shared__ uint32_t sidx[TCHUNK + 2];
        const int w     = bid % NW;
        const int chunk = bid / NW;
        const int t0    = chunk * TCHUNK;
        const int len   = min(TCHUNK, TN - t0);   // 128 except last chunk (126)
        const int rows  = len + 2;

        // build packed level indices for this t-slice (round-half-even == np.round)
        for (int i = l; i < rows; i += 64) {
            const float4 s = ((const float4*)signals)[t0 + i];
            uint32_t iw;
            {
                float x0 = rintf(fminf(fmaxf(s.x, 0.f), 1.f) * 99.0f);
                float x1 = rintf(fminf(fmaxf(s.y, 0.f), 1.f) * 99.0f);
                float x2 = rintf(fminf(fmaxf(s.z, 0.f), 1.f) * 99.0f);
                float x3 = rintf(fminf(fmaxf(s.w, 0.f), 1.f) * 99.0f);
                iw  = (uint32_t)(int)x0;
                iw |= (uint32_t)(int)x1 << 8;
                iw |= (uint32_t)(int)x2 << 16;
                iw |= (uint32_t)(int)x3 << 24;
            }
            sidx[i] = iw;
        }
        __syncthreads();

        const int rc = (w * 62 + l + (D - 2)) % D;   // row col for this lane
        const float k0 = keys[rc];
        const float k1 = keys[D + rc];
        const float k2 = keys[2 * D + rc];
        const float k3 = keys[3 * D + rc];

        auto row = [&](int i) -> float {
            const uint32_t iw = sidx[i];             // LDS broadcast (uniform addr)
            const int l0 = iw & 0xff;
            const int l1 = (iw >> 8) & 0xff;
            const int l2 = (iw >> 16) & 0xff;
            const int l3 = iw >> 24;
            float r = k0 * lw[l0 * D + rc];
            r = fmaf(k1, lw[l1 * D + rc], r);
            r = fmaf(k2, lw[l2 * D + rc], r);
            r = fmaf(k3, lw[l3 * D + rc], r);
            return r;
        };

        float a = row(0);      // p[t]
        float b = row(1);      // p[t+1]
        float accv = 0.f;
        if (len == TCHUNK) {
            #pragma unroll 4
            for (int i = 0; i < TCHUNK; ++i) {
                const float c = row(i + 2);          // p[t+2]
                const float a2 = __shfl_up(a, 2, 64);
                const float b1 = __shfl_up(b, 1, 64);
                accv = fmaf(a2 * b1, c, accv);       // exact small-int arithmetic
                a = b; b = c;
            }
        } else {
            for (int i = 0; i < len; ++i) {
                const float c = row(i + 2);
                const float a2 = __shfl_up(a, 2, 64);
                const float b1 = __shfl_up(b, 1, 64);
                accv = fmaf(a2 * b1, c, accv);
                a = b; b = c;
            }
        }
        const int outcol = w * 62 + l - 2;
        if (l >= 2 && outcol < D) ws[chunk * D + outcol] = accv;  // plain store
    } else {
        // ---- mhv part: one (k,d) dot per thread, float4 loads after peel ----
        const int gid = (bid - NGBLK) * 64 + l;
        if (gid < MHVTH) {
            const int k = gid / D;                       // 0..5
            const float* __restrict__ mf   = feat + k * 91;
            const float* __restrict__ wrow = mfcc_w + (size_t)gid * 91;
            const int p = (4 - ((gid * 91) & 3)) & 3;    // peel to 16B alignment
            float s = 0.f;
            for (int f = 0; f < p; ++f) s = fmaf(wrow[f], mf[f], s);
            const float4* __restrict__ v = (const float4*)(wrow + p);
            #pragma unroll 2
            for (int j = 0; j < 22; ++j) {               // nv4 == 22 for all p
                const float4 x = v[j];
                const int f0 = p + 4 * j;
                s = fmaf(x.x, mf[f0],     s);
                s = fmaf(x.y, mf[f0 + 1], s);
                s = fmaf(x.z, mf[f0 + 2], s);
                s = fmaf(x.w, mf[f0 + 3], s);
            }
            for (int f = p + 88; f < 91; ++f) s = fmaf(wrow[f], mf[f], s);
            ws[NCHUNK * D + gid] = cosf(s + mfcc_b[gid]) * sinf(s);
        }
    }
}

// ---------------- kB: partial-sum, 29 sinusoid kernels, comb, quantize ----------------
__global__ __launch_bounds__(64) void kB(
    const float* __restrict__ feat,
    const float* __restrict__ feat_w,   // [29,D]
    const float* __restrict__ feat_b,   // [29,D]
    float* __restrict__ out,
    const float* __restrict__ ws)
{
    static const int CF[29] = {547,548,549,551,554,556,557,558,559,560,561,562,563,565,
                               566,567,570,576,580,581,582,583,584,585,588,593,598,599,600};
    const int d = blockIdx.x * 64 + threadIdx.x;
    if (d >= D) return;

    float acc = 0.f;
    #pragma unroll
    for (int c = 0; c < NCHUNK; ++c) acc += ws[c * D + d];   // exact ints, |sum|<2^24

    const float* __restrict__ mhv = ws + NCHUNK * D;
    float mfp = mhv[d];
    #pragma unroll
    for (int k = 1; k < 6; ++k) mfp *= mhv[k * D + d];

    float h[29];
    #pragma unroll
    for (int i = 0; i < 29; ++i) {
        const float sel  = feat[CF[i] - 1];                  // uniform scalar load
        const float proj = sel * feat_w[i * D + d];
        h[i] = cosf(proj + feat_b[i * D + d]) * sinf(proj);
    }

    const float comb = h[0] * h[8] * h[13]
                     + h[1] * h[9] * h[14]
                     + h[2] * h[10] * h[15]
                     + h[3] * h[4]
                     + h[5] * h[7] * h[22] * h[6] * h[23] * h[19] * h[18]
                       * h[20] * h[21] * h[26] * h[28] * h[27]
                     + h[11] + h[12]
                     + h[16] * h[24]
                     + h[17] + h[25]
                     + mfp;

    const float sv = acc * comb;
    out[d] = sv > 0.f ? 1.f : -1.f;
}

extern "C" void kernel_launch(void* const* d_in, const int* in_sizes, int n_in,
                              void* d_out, int out_size, void* d_ws, size_t ws_size,
                              hipStream_t stream) {
    const float* signals = (const float*)d_in[0];
    const float* feat    = (const float*)d_in[1];
    const float* keys    = (const float*)d_in[2];
    const float* lw      = (const float*)d_in[3];
    const float* feat_w  = (const float*)d_in[4];
    const float* feat_b  = (const float*)d_in[5];
    const float* mfcc_w  = (const float*)d_in[6];
    const float* mfcc_b  = (const float*)d_in[7];
    float* ws  = (float*)d_ws;
    float* out = (float*)d_out;

    kA<<<dim3(NGBLK + MHVBLK), dim3(64), 0, stream>>>(signals, feat, keys, lw,
                                                      mfcc_w, mfcc_b, ws);
    kB<<<dim3((D + 63) / 64), dim3(64), 0, stream>>>(feat, feat_w, feat_b, out, ws);
}

// Round 4
// 119.336 us; speedup vs baseline: 1.0977x; 1.0901x over previous
//
#include <hip/hip_runtime.h>
#include <stdint.h>

#define D 10000
#define T 2048
#define TN 2046            // T - NGRAM + 1
#define NWIN 40            // column windows
#define WSTRIDE 252        // out-cols per window (252*40 = 10080 >= D)
#define TCHB 256           // t-steps per ngram block (4 waves x 64)
#define NYB 8              // 8 block-groups * 256 t = 2048
#define NCH 32             // partial chunks (one per wave)
#define NGB (NWIN * NYB)          // 320 ngram blocks
#define MHVTH (6 * D)             // 60000 mfcc threads
#define MHVBLK ((MHVTH + 255) / 256)  // 235

// ws layout (floats): partial[NCH][D] @ 0 ; mhv[6][D] @ NCH*D
// Every slot written unconditionally -> no zero-init needed despite 0xAA poison.

// ---------------- kA: fused MFCC sinusoid HVs + ngram encode ----------------
__global__ __launch_bounds__(256) void kA(
    const float* __restrict__ signals,   // [T,4]
    const float* __restrict__ feat,      // [600]
    const float* __restrict__ keys,      // [4,D]
    const float* __restrict__ lw,        // [100,D]
    const float* __restrict__ mfcc_w,    // [6,D,91]
    const float* __restrict__ mfcc_b,    // [6,D]
    float* __restrict__ ws)
{
    const int bid = blockIdx.x;
    const int tid = threadIdx.x;

    if (bid < MHVBLK) {
        // ---- mhv: one (k,d) dot per thread, float4 loads after align-peel ----
        const int gid = bid * 256 + tid;
        if (gid < MHVTH) {
            const int k = gid / D;                       // 0..5
            const float* __restrict__ mf   = feat + k * 91;
            const float* __restrict__ wrow = mfcc_w + (size_t)gid * 91;
            const int p = (4 - ((gid * 91) & 3)) & 3;    // peel to 16B alignment
            float s = 0.f;
            for (int f = 0; f < p; ++f) s = fmaf(wrow[f], mf[f], s);
            const float4* __restrict__ v = (const float4*)(wrow + p);
            #pragma unroll 2
            for (int j = 0; j < 22; ++j) {               // 22 float4s for all p
                const float4 x = v[j];
                const int f0 = p + 4 * j;
                s = fmaf(x.x, mf[f0],     s);
                s = fmaf(x.y, mf[f0 + 1], s);
                s = fmaf(x.z, mf[f0 + 2], s);
                s = fmaf(x.w, mf[f0 + 3], s);
            }
            for (int f = p + 88; f < 91; ++f) s = fmaf(wrow[f], mf[f], s);
            ws[NCH * D + gid] = cosf(s + mfcc_b[gid]) * sinf(s);
        }
        return;
    }

    // ---- ngram: block = 4 waves; wave = one 64-t chunk of one 256-col window ----
    __shared__ uint32_t sidx[TCHB + 2];
    const int nb   = bid - MHVBLK;
    const int w    = nb % NWIN;
    const int yb   = nb / NWIN;
    const int t0b  = yb * TCHB;
    const int need = min(TCHB + 2, T - t0b);

    for (int i = tid; i < need; i += 256) {
        const float4 s = ((const float4*)signals)[t0b + i];
        uint32_t iw;
        {   // round-half-even == np.round
            const float x0 = rintf(fminf(fmaxf(s.x, 0.f), 1.f) * 99.0f);
            const float x1 = rintf(fminf(fmaxf(s.y, 0.f), 1.f) * 99.0f);
            const float x2 = rintf(fminf(fmaxf(s.z, 0.f), 1.f) * 99.0f);
            const float x3 = rintf(fminf(fmaxf(s.w, 0.f), 1.f) * 99.0f);
            iw  = (uint32_t)(int)x0;
            iw |= (uint32_t)(int)x1 << 8;
            iw |= (uint32_t)(int)x2 << 16;
            iw |= (uint32_t)(int)x3 << 24;
        }
        sidx[i] = iw;
    }
    __syncthreads();

    const int wv    = tid >> 6;
    const int l     = tid & 63;
    const int chunk = yb * 4 + wv;
    const int t0    = chunk * 64;
    const int len   = min(64, TN - t0);    // 64, last chunk 62
    const int so    = wv * 64;

    // column base: rb = w*252 - 4 (mod D); rb,c0 always 0 mod 4 -> aligned float4
    const int rb = (w * WSTRIDE + D - 4) % D;
    int c0 = rb + 4 * l; if (c0 >= D) c0 -= D;

    const float4 k0 = *(const float4*)(keys + 0 * D + c0);
    const float4 k1 = *(const float4*)(keys + 1 * D + c0);
    const float4 k2 = *(const float4*)(keys + 2 * D + c0);
    const float4 k3 = *(const float4*)(keys + 3 * D + c0);

    auto row = [&](int i) -> float4 {
        const uint32_t iw = sidx[so + i];            // uniform LDS broadcast
        const float4 v0 = *(const float4*)(lw + (iw & 0xffu) * D + c0);
        const float4 v1 = *(const float4*)(lw + ((iw >> 8) & 0xffu) * D + c0);
        const float4 v2 = *(const float4*)(lw + ((iw >> 16) & 0xffu) * D + c0);
        const float4 v3 = *(const float4*)(lw + (iw >> 24) * D + c0);
        float4 r;
        r.x = fmaf(k3.x, v3.x, fmaf(k2.x, v2.x, fmaf(k1.x, v1.x, k0.x * v0.x)));
        r.y = fmaf(k3.y, v3.y, fmaf(k2.y, v2.y, fmaf(k1.y, v1.y, k0.y * v0.y)));
        r.z = fmaf(k3.z, v3.z, fmaf(k2.z, v2.z, fmaf(k1.z, v1.z, k0.z * v0.z)));
        r.w = fmaf(k3.w, v3.w, fmaf(k2.w, v2.w, fmaf(k1.w, v1.w, k0.w * v0.w)));
        return r;
    };

    float4 a = row(0);     // p[t]
    float4 b = row(1);     // p[t+1]
    float4 acc = make_float4(0.f, 0.f, 0.f, 0.f);

    #pragma unroll 4
    for (int i = 0; i < len; ++i) {
        const float4 c = row(i + 2);                 // p[t+2]
        const float b3u = __shfl_up(b.w, 1, 64);     // p[t+1][c0-1]
        const float a2u = __shfl_up(a.z, 1, 64);     // p[t][c0-2]
        const float a3u = __shfl_up(a.w, 1, 64);     // p[t][c0-1]
        acc.x = fmaf(a2u * b3u, c.x, acc.x);         // exact small-int arithmetic
        acc.y = fmaf(a3u * b.x, c.y, acc.y);
        acc.z = fmaf(a.x * b.y, c.z, acc.z);
        acc.w = fmaf(a.y * b.z, c.w, acc.w);
        a = b; b = c;
    }

    const int ocb = w * WSTRIDE + 4 * (l - 1);       // out-col base (j=0)
    if (l >= 1 && ocb + 3 < D)
        *(float4*)(ws + chunk * D + ocb) = acc;      // plain aligned store
}

// ---------------- kB: partial-sum, 29 sinusoid kernels, comb, quantize ----------------
__global__ __launch_bounds__(64) void kB(
    const float* __restrict__ feat,
    const float* __restrict__ feat_w,   // [29,D]
    const float* __restrict__ feat_b,   // [29,D]
    float* __restrict__ out,
    const float* __restrict__ ws)
{
    static const int CF[29] = {547,548,549,551,554,556,557,558,559,560,561,562,563,565,
                               566,567,570,576,580,581,582,583,584,585,588,593,598,599,600};
    const int d = blockIdx.x * 64 + threadIdx.x;
    if (d >= D) return;

    float acc = 0.f;
    #pragma unroll
    for (int c = 0; c < NCH; ++c) acc += ws[c * D + d];   // exact ints, |sum|<2^24

    const float* __restrict__ mhv = ws + NCH * D;
    float mfp = mhv[d];
    #pragma unroll
    for (int k = 1; k < 6; ++k) mfp *= mhv[k * D + d];

    float h[29];
    #pragma unroll
    for (int i = 0; i < 29; ++i) {
        const float sel  = feat[CF[i] - 1];               // uniform scalar load
        const float proj = sel * feat_w[i * D + d];
        h[i] = cosf(proj + feat_b[i * D + d]) * sinf(proj);
    }

    const float comb = h[0] * h[8] * h[13]
                     + h[1] * h[9] * h[14]
                     + h[2] * h[10] * h[15]
                     + h[3] * h[4]
                     + h[5] * h[7] * h[22] * h[6] * h[23] * h[19] * h[18]
                       * h[20] * h[21] * h[26] * h[28] * h[27]
                     + h[11] + h[12]
                     + h[16] * h[24]
                     + h[17] + h[25]
                     + mfp;

    const float sv = acc * comb;
    out[d] = sv > 0.f ? 1.f : -1.f;
}

extern "C" void kernel_launch(void* const* d_in, const int* in_sizes, int n_in,
                              void* d_out, int out_size, void* d_ws, size_t ws_size,
                              hipStream_t stream) {
    const float* signals = (const float*)d_in[0];
    const float* feat    = (const float*)d_in[1];
    const float* keys    = (const float*)d_in[2];
    const float* lw      = (const float*)d_in[3];
    const float* feat_w  = (const float*)d_in[4];
    const float* feat_b  = (const float*)d_in[5];
    const float* mfcc_w  = (const float*)d_in[6];
    const float* mfcc_b  = (const float*)d_in[7];
    float* ws  = (float*)d_ws;
    float* out = (float*)d_out;

    kA<<<dim3(MHVBLK + NGB), dim3(256), 0, stream>>>(signals, feat, keys, lw,
                                                     mfcc_w, mfcc_b, ws);
    kB<<<dim3((D + 63) / 64), dim3(64), 0, stream>>>(feat, feat_w, feat_b, out, ws);
}

// Round 5
// 107.424 us; speedup vs baseline: 1.2195x; 1.1109x over previous
//
#include <hip/hip_runtime.h>
#include <stdint.h>

#define D 10000
#define T 2048
#define TN 2046            // T - NGRAM + 1
#define NWIN 40            // column windows
#define WSTRIDE 252        // out-cols per window (252*40 = 10080 >= D)
#define TCHB 256           // t-steps per ngram block (4 waves x 64)
#define NYB 8              // 8 block-groups * 256 t = 2048
#define NCH 32             // partial chunks (one per wave)
#define NGB (NWIN * NYB)          // 320 ngram blocks
#define MHVTH (6 * D)             // 60000 mfcc threads
#define MHVBLK ((MHVTH + 255) / 256)  // 235
#define CHB ((D + 255) / 256)         // 40 combH blocks

// ws layout (floats): partial[NCH][D] @ 0 ; mhv[6][D] @ NCH*D ; combH[D] @ (NCH+6)*D
// Every slot written unconditionally -> no zero-init needed despite 0xAA poison.

// ---------------- kA: fused MFCC HVs + ngram encode + 29-sinusoid comb ----------------
__global__ __launch_bounds__(256) void kA(
    const float* __restrict__ signals,   // [T,4]
    const float* __restrict__ feat,      // [600]
    const float* __restrict__ keys,      // [4,D]
    const float* __restrict__ lw,        // [100,D]
    const float* __restrict__ mfcc_w,    // [6,D,91]
    const float* __restrict__ mfcc_b,    // [6,D]
    const float* __restrict__ feat_w,    // [29,D]
    const float* __restrict__ feat_b,    // [29,D]
    float* __restrict__ ws)
{
    const int bid = blockIdx.x;
    const int tid = threadIdx.x;

    if (bid < MHVBLK) {
        // ---- mhv: one (k,d) dot per thread, float4 loads after align-peel ----
        const int gid = bid * 256 + tid;
        if (gid < MHVTH) {
            const int k = gid / D;                       // 0..5
            const float* __restrict__ mf   = feat + k * 91;
            const float* __restrict__ wrow = mfcc_w + (size_t)gid * 91;
            const int p = (4 - ((gid * 91) & 3)) & 3;    // peel to 16B alignment
            float s = 0.f;
            for (int f = 0; f < p; ++f) s = fmaf(wrow[f], mf[f], s);
            const float4* __restrict__ v = (const float4*)(wrow + p);
            #pragma unroll 2
            for (int j = 0; j < 22; ++j) {               // 22 float4s for all p
                const float4 x = v[j];
                const int f0 = p + 4 * j;
                s = fmaf(x.x, mf[f0],     s);
                s = fmaf(x.y, mf[f0 + 1], s);
                s = fmaf(x.z, mf[f0 + 2], s);
                s = fmaf(x.w, mf[f0 + 3], s);
            }
            for (int f = p + 88; f < 91; ++f) s = fmaf(wrow[f], mf[f], s);
            ws[NCH * D + gid] = cosf(s + mfcc_b[gid]) * sinf(s);
        }
        return;
    }

    if (bid >= MHVBLK + NGB) {
        // ---- combH: 29 sinusoid kernels + h-combination (independent of mhv/ngram) ----
        static const int CF[29] = {547,548,549,551,554,556,557,558,559,560,561,562,563,565,
                                   566,567,570,576,580,581,582,583,584,585,588,593,598,599,600};
        const int d = (bid - MHVBLK - NGB) * 256 + tid;
        if (d < D) {
            float h[29];
            #pragma unroll
            for (int i = 0; i < 29; ++i) {
                const float sel  = feat[CF[i] - 1];          // uniform scalar load
                const float proj = sel * feat_w[i * D + d];
                h[i] = cosf(proj + feat_b[i * D + d]) * sinf(proj);
            }
            const float combH = h[0] * h[8] * h[13]
                              + h[1] * h[9] * h[14]
                              + h[2] * h[10] * h[15]
                              + h[3] * h[4]
                              + h[5] * h[7] * h[22] * h[6] * h[23] * h[19] * h[18]
                                * h[20] * h[21] * h[26] * h[28] * h[27]
                              + h[11] + h[12]
                              + h[16] * h[24]
                              + h[17] + h[25];
            ws[(NCH + 6) * D + d] = combH;
        }
        return;
    }

    // ---- ngram: block = 4 waves; wave = one 64-t chunk of one 256-col window ----
    __shared__ uint32_t sidx[TCHB + 2];
    const int nb   = bid - MHVBLK;
    const int w    = nb % NWIN;
    const int yb   = nb / NWIN;
    const int t0b  = yb * TCHB;
    const int need = min(TCHB + 2, T - t0b);

    for (int i = tid; i < need; i += 256) {
        const float4 s = ((const float4*)signals)[t0b + i];
        uint32_t iw;
        {   // round-half-even == np.round
            const float x0 = rintf(fminf(fmaxf(s.x, 0.f), 1.f) * 99.0f);
            const float x1 = rintf(fminf(fmaxf(s.y, 0.f), 1.f) * 99.0f);
            const float x2 = rintf(fminf(fmaxf(s.z, 0.f), 1.f) * 99.0f);
            const float x3 = rintf(fminf(fmaxf(s.w, 0.f), 1.f) * 99.0f);
            iw  = (uint32_t)(int)x0;
            iw |= (uint32_t)(int)x1 << 8;
            iw |= (uint32_t)(int)x2 << 16;
            iw |= (uint32_t)(int)x3 << 24;
        }
        sidx[i] = iw;
    }
    __syncthreads();

    const int wv    = tid >> 6;
    const int l     = tid & 63;
    const int chunk = yb * 4 + wv;
    const int t0    = chunk * 64;
    const int len   = min(64, TN - t0);    // 64, last chunk 62
    const int so    = wv * 64;

    // column base: rb = w*252 - 4 (mod D); rb,c0 always 0 mod 4 -> aligned float4
    const int rb = (w * WSTRIDE + D - 4) % D;
    int c0 = rb + 4 * l; if (c0 >= D) c0 -= D;

    const float4 k0 = *(const float4*)(keys + 0 * D + c0);
    const float4 k1 = *(const float4*)(keys + 1 * D + c0);
    const float4 k2 = *(const float4*)(keys + 2 * D + c0);
    const float4 k3 = *(const float4*)(keys + 3 * D + c0);

    auto row = [&](int i) -> float4 {
        const uint32_t iw = sidx[so + i];            // uniform LDS broadcast
        const float4 v0 = *(const float4*)(lw + (iw & 0xffu) * D + c0);
        const float4 v1 = *(const float4*)(lw + ((iw >> 8) & 0xffu) * D + c0);
        const float4 v2 = *(const float4*)(lw + ((iw >> 16) & 0xffu) * D + c0);
        const float4 v3 = *(const float4*)(lw + (iw >> 24) * D + c0);
        float4 r;
        r.x = fmaf(k3.x, v3.x, fmaf(k2.x, v2.x, fmaf(k1.x, v1.x, k0.x * v0.x)));
        r.y = fmaf(k3.y, v3.y, fmaf(k2.y, v2.y, fmaf(k1.y, v1.y, k0.y * v0.y)));
        r.z = fmaf(k3.z, v3.z, fmaf(k2.z, v2.z, fmaf(k1.z, v1.z, k0.z * v0.z)));
        r.w = fmaf(k3.w, v3.w, fmaf(k2.w, v2.w, fmaf(k1.w, v1.w, k0.w * v0.w)));
        return r;
    };

    float4 a = row(0);     // p[t]
    float4 b = row(1);     // p[t+1]
    float4 acc = make_float4(0.f, 0.f, 0.f, 0.f);

    #pragma unroll 4
    for (int i = 0; i < len; ++i) {
        const float4 c = row(i + 2);                 // p[t+2]
        const float b3u = __shfl_up(b.w, 1, 64);     // p[t+1][c0-1]
        const float a2u = __shfl_up(a.z, 1, 64);     // p[t][c0-2]
        const float a3u = __shfl_up(a.w, 1, 64);     // p[t][c0-1]
        acc.x = fmaf(a2u * b3u, c.x, acc.x);         // exact small-int arithmetic
        acc.y = fmaf(a3u * b.x, c.y, acc.y);
        acc.z = fmaf(a.x * b.y, c.z, acc.z);
        acc.w = fmaf(a.y * b.z, c.w, acc.w);
        a = b; b = c;
    }

    const int ocb = w * WSTRIDE + 4 * (l - 1);       // out-col base (j=0)
    if (l >= 1 && ocb + 3 < D)
        *(float4*)(ws + chunk * D + ocb) = acc;      // plain aligned store
}

// ---------------- kB: partial-sum + mhv product + comb + quantize (trivial) ----------------
__global__ __launch_bounds__(256) void kB(
    float* __restrict__ out,
    const float* __restrict__ ws)
{
    const int d = blockIdx.x * 256 + threadIdx.x;
    if (d >= D) return;

    float acc = 0.f;
    #pragma unroll
    for (int c = 0; c < NCH; ++c) acc += ws[c * D + d];   // exact ints, |sum|<2^24

    const float* __restrict__ mhv = ws + NCH * D;
    float mfp = mhv[d];
    #pragma unroll
    for (int k = 1; k < 6; ++k) mfp *= mhv[k * D + d];

    const float comb = ws[(NCH + 6) * D + d] + mfp;       // same FP order as reference
    const float sv = acc * comb;
    out[d] = sv > 0.f ? 1.f : -1.f;
}

extern "C" void kernel_launch(void* const* d_in, const int* in_sizes, int n_in,
                              void* d_out, int out_size, void* d_ws, size_t ws_size,
                              hipStream_t stream) {
    const float* signals = (const float*)d_in[0];
    const float* feat    = (const float*)d_in[1];
    const float* keys    = (const float*)d_in[2];
    const float* lw      = (const float*)d_in[3];
    const float* feat_w  = (const float*)d_in[4];
    const float* feat_b  = (const float*)d_in[5];
    const float* mfcc_w  = (const float*)d_in[6];
    const float* mfcc_b  = (const float*)d_in[7];
    float* ws  = (float*)d_ws;
    float* out = (float*)d_out;

    kA<<<dim3(MHVBLK + NGB + CHB), dim3(256), 0, stream>>>(signals, feat, keys, lw,
                                                           mfcc_w, mfcc_b,
                                                           feat_w, feat_b, ws);
    kB<<<dim3(CHB), dim3(256), 0, stream>>>(out, ws);
}